// Round 18
// baseline (79.083 us; speedup 1.0000x reference)
//
#include <hip/hip_runtime.h>
#include <hip/hip_bf16.h>

// ---------------------------------------------------------------------------
// MockModularAttention: Q/K/V proj -> sigmoid/Horner causal attention -> out proj
// B=2, L=2048, E=512, H=8, Hd=64. bf16 MFMA, fp32 accum.
// Attention: KV-split, slotted atomic-free partials, single-buffer staging +
// T14 prefetch, swapped QK^T + bpermute (round-15/17 proven tile loop).
// THIS ROUND: chunk=8 (was 4) -> slots per head 144->80: attn partial writes
// and combine reads halve; 1280 jobs = exactly one residency generation.
// Summation order unchanged -> bitwise-identical output.
// ---------------------------------------------------------------------------

typedef __attribute__((ext_vector_type(8))) __bf16 bf16x8;
typedef __attribute__((ext_vector_type(4))) __bf16 bf16x4;
typedef __attribute__((ext_vector_type(4))) float f32x4;
typedef __attribute__((ext_vector_type(4))) int i32x4;

#define NB 2
#define NL 2048
#define NE 512
#define NH 8
#define HD 64
#define NROW (NB * NL)  // 4096
#define NJOB 80         // KV-split jobs (= slots) per (b,h), chunk=8

__device__ __forceinline__ void gload16(const void* g, void* l) {
  __builtin_amdgcn_global_load_lds(
      (const __attribute__((address_space(1))) void*)g,
      (__attribute__((address_space(3))) void*)l, 16, 0, 0);
}

// ---------------------------------------------------------------------------
// Single fused fp32->bf16 conversion: query,key_,value (each 2^19 float4)
// then Wq,Wk,Wv,Wo (each 2^16 float4). Grid: 7168 x 256 threads, exact.
// ---------------------------------------------------------------------------
__global__ __launch_bounds__(256) void cvt_all(
    const float* __restrict__ q, const float* __restrict__ k,
    const float* __restrict__ v, const float* __restrict__ w0,
    const float* __restrict__ w1, const float* __restrict__ w2,
    const float* __restrict__ w3, __bf16* __restrict__ qo,
    __bf16* __restrict__ ko, __bf16* __restrict__ vo, __bf16* __restrict__ o0,
    __bf16* __restrict__ o1, __bf16* __restrict__ o2,
    __bf16* __restrict__ o3) {
  const int gid = blockIdx.x * 256 + threadIdx.x;
  const float* s;
  __bf16* d;
  int i;
  if (gid < 3 * (1 << 19)) {
    const int seg = gid >> 19;
    i = gid & ((1 << 19) - 1);
    s = seg == 0 ? q : (seg == 1 ? k : v);
    d = seg == 0 ? qo : (seg == 1 ? ko : vo);
  } else {
    const int wid = gid - 3 * (1 << 19);
    const int seg = wid >> 16;
    i = wid & 0xFFFF;
    s = seg == 0 ? w0 : (seg == 1 ? w1 : (seg == 2 ? w2 : w3));
    d = seg == 0 ? o0 : (seg == 1 ? o1 : (seg == 2 ? o2 : o3));
  }
  float4 x = ((const float4*)s)[i];
  bf16x4 o = {(__bf16)x.x, (__bf16)x.y, (__bf16)x.z, (__bf16)x.w};
  ((bf16x4*)d)[i] = o;
}

// ---------------------------------------------------------------------------
// GEMM body (round-9 proven, 128x128 tile, BK=32, 4 waves, global_load_lds)
// MODE 0: bf16 out, head layout (B,H,L,Hd).
// MODE 1: fp32 out, (row, col).
// MODE 2: bf16 out, TRANSPOSED head layout (B,H,Hd,L)  [for V]
// ---------------------------------------------------------------------------
template <int MODE>
__device__ __forceinline__ void gemm_body(const __bf16* __restrict__ A,
                                          const __bf16* __restrict__ W,
                                          const float* __restrict__ bias,
                                          __bf16* __restrict__ outb,
                                          float* __restrict__ outf) {
  __shared__ __align__(16) __bf16 As[128 * 32];
  __shared__ __align__(16) __bf16 Ws[128 * 32];

  const int tid = threadIdx.x;
  const int lane = tid & 63, w = tid >> 6;
  const int lr = lane & 15, lg = lane >> 4;
  const int brow = blockIdx.y * 128, bcol = blockIdx.x * 128;
  const int wr = (w >> 1) * 64, wc = (w & 1) * 64;

  f32x4 zero4 = {0.f, 0.f, 0.f, 0.f};
  f32x4 acc[4][4];
#pragma unroll
  for (int i = 0; i < 4; ++i)
#pragma unroll
    for (int j = 0; j < 4; ++j) acc[i][j] = zero4;

  const int c0 = tid, c1 = tid + 256;
  const int r0 = c0 >> 2, cc0 = c0 & 3;
  const int r1 = c1 >> 2, cc1 = c1 & 3;

  for (int k0 = 0; k0 < NE; k0 += 32) {
    __syncthreads();
    gload16(A + (size_t)(brow + r0) * NE + k0 + cc0 * 8, As + c0 * 8);
    gload16(W + (size_t)(bcol + r0) * NE + k0 + cc0 * 8, Ws + c0 * 8);
    gload16(A + (size_t)(brow + r1) * NE + k0 + cc1 * 8, As + c1 * 8);
    gload16(W + (size_t)(bcol + r1) * NE + k0 + cc1 * 8, Ws + c1 * 8);
    __syncthreads();

    bf16x8 af[4], wf[4];
#pragma unroll
    for (int mi = 0; mi < 4; ++mi)
      af[mi] = *(const bf16x8*)(As + (wr + mi * 16 + lr) * 32 + lg * 8);
#pragma unroll
    for (int ni = 0; ni < 4; ++ni)
      wf[ni] = *(const bf16x8*)(Ws + (wc + ni * 16 + lr) * 32 + lg * 8);
#pragma unroll
    for (int mi = 0; mi < 4; ++mi)
#pragma unroll
      for (int ni = 0; ni < 4; ++ni)
        acc[mi][ni] = __builtin_amdgcn_mfma_f32_16x16x32_bf16(
            af[mi], wf[ni], acc[mi][ni], 0, 0, 0);
  }

#pragma unroll
  for (int mi = 0; mi < 4; ++mi) {
#pragma unroll
    for (int ni = 0; ni < 4; ++ni) {
      const int col = bcol + wc + ni * 16 + lr;
      const float bv = bias[col];
#pragma unroll
      for (int r = 0; r < 4; ++r) {
        const int row = brow + wr + mi * 16 + lg * 4 + r;
        const float v = acc[mi][ni][r] + bv;
        if (MODE == 0) {
          const int b = row >> 11, l = row & (NL - 1);
          const int h = col >> 6, d = col & 63;
          outb[(((size_t)b * NH + h) * NL + l) * HD + d] = (__bf16)v;
        } else if (MODE == 2) {
          const int b = row >> 11, l = row & (NL - 1);
          const int h = col >> 6, d = col & 63;
          outb[(((size_t)b * NH + h) * HD + d) * NL + l] = (__bf16)v;
        } else {
          outf[(size_t)row * NE + col] = v;
        }
      }
    }
  }
}

// Fused Q/K/V projections: grid.z selects; V (z=2) writes transposed layout.
__global__ __launch_bounds__(256) void qkv_gemm(
    const __bf16* __restrict__ A0, const __bf16* __restrict__ A1,
    const __bf16* __restrict__ A2, const __bf16* __restrict__ W0,
    const __bf16* __restrict__ W1, const __bf16* __restrict__ W2,
    const float* __restrict__ b0, const float* __restrict__ b1,
    const float* __restrict__ b2, __bf16* __restrict__ O0,
    __bf16* __restrict__ O1, __bf16* __restrict__ O2) {
  const int z = blockIdx.z;
  if (z == 2) {
    gemm_body<2>(A2, W2, b2, O2, nullptr);
  } else {
    const __bf16* A = z == 0 ? A0 : A1;
    const __bf16* W = z == 0 ? W0 : W1;
    const float* bias = z == 0 ? b0 : b1;
    __bf16* O = z == 0 ? O0 : O1;
    gemm_body<0>(A, W, bias, O, nullptr);
  }
}

__global__ __launch_bounds__(256) void out_gemm(const __bf16* __restrict__ A,
                                                const __bf16* __restrict__ W,
                                                const float* __restrict__ bias,
                                                float* __restrict__ outf) {
  gemm_body<1>(A, W, bias, nullptr, outf);
}

// ---------------------------------------------------------------------------
// KV-split causal attention, sigmoid/Horner. Chunk=8, slotted partials.
// Job -> (qb, c) decode from round 7 (verified): counts 32,24,16,8.
// Tile loop byte-identical to round 15/17.
// ---------------------------------------------------------------------------
template <int SLOTTED>
__global__ __launch_bounds__(256) void attn_kernel(
    const __bf16* __restrict__ Qg, const __bf16* __restrict__ Kg,
    const __bf16* __restrict__ VTg, float* __restrict__ numg,
    float* __restrict__ deng, const float* __restrict__ log_tau) {
  // rows padded to 72 bf16 (144 B = 9*16B): b128-aligned reads
  __shared__ __align__(16) __bf16 Kt[64][72];
  __shared__ __align__(16) __bf16 Vt[64][72];  // Vt[d][s] = V[s][d]

  // job -> (qb, c); chunk c covers qb in [8c, 31].
  const int j = blockIdx.x;
  int qb, c;
  if (j < 32) {
    c = 0; qb = j;
  } else if (j < 56) {
    c = 1; qb = j - 24;  // 8 + (j-32)
  } else if (j < 72) {
    c = 2; qb = j - 40;  // 16 + (j-56)
  } else {
    c = 3; qb = j - 48;  // 24 + (j-72)
  }
  const int bh = blockIdx.y;  // b*NH + h
  const __bf16* Qh = Qg + (size_t)bh * NL * HD;
  const __bf16* Kh = Kg + (size_t)bh * NL * HD;
  const __bf16* Vth = VTg + (size_t)bh * HD * NL;  // (Hd, L) for this head

  const int tid = threadIdx.x;
  const int lane = tid & 63, w = tid >> 6;
  const int lr = lane & 15, lg = lane >> 4;
  // sigmoid(s/(8*tau)) = rcp(1 + exp2(s*ninv)), ninv = -log2(e)/(8*tau)
  const float ninv = -1.44269504f / (8.0f * __expf(log_tau[0]));

  const int q0 = qb * 64;
  const int qg = q0 + w * 16 + lr;  // this lane's q-row (swapped layout)
  bf16x8 qf[2];
  qf[0] = *(const bf16x8*)(Qh + (size_t)qg * HD + lg * 8);
  qf[1] = *(const bf16x8*)(Qh + (size_t)qg * HD + 32 + lg * 8);

  f32x4 zero4 = {0.f, 0.f, 0.f, 0.f};
  f32x4 o_acc[4];
#pragma unroll
  for (int n = 0; n < 4; ++n) o_acc[n] = zero4;
  float den_l = 0.f;  // lane-local partial over this lane's s-subset

  const int t0 = c * 8;
  const int t1 = min(t0 + 8, qb + 1);

  // staging partition: thread -> rows {kr0, kr0+32}, cols kc0..kc0+7.
  const int kr0 = tid >> 3, kc0 = (tid & 7) * 8;

  // prologue: load tile t0 into registers
  bf16x8 kpa = *(const bf16x8*)(Kh + (size_t)(t0 * 64 + kr0) * HD + kc0);
  bf16x8 kpb = *(const bf16x8*)(Kh + (size_t)(t0 * 64 + kr0 + 32) * HD + kc0);
  bf16x8 vpa = *(const bf16x8*)(Vth + (size_t)kr0 * NL + t0 * 64 + kc0);
  bf16x8 vpb = *(const bf16x8*)(Vth + (size_t)(kr0 + 32) * NL + t0 * 64 + kc0);

  // bpermute byte-index of source lane A ((lg&1)*32 + lr); B = +16 lanes
  const int idxA = (((lane & 16) << 1) + lr) * 4;
  const bool hi = (lane & 32) != 0;  // lg>>1: selects si tile parity

  for (int t = t0; t < t1; ++t) {
    const int kv0 = t * 64;
    __syncthreads();  // previous iter's LDS reads done before overwrite
    *(bf16x8*)&Kt[kr0][kc0] = kpa;
    *(bf16x8*)&Kt[kr0 + 32][kc0] = kpb;
    *(bf16x8*)&Vt[kr0][kc0] = vpa;
    *(bf16x8*)&Vt[kr0 + 32][kc0] = vpb;
    __syncthreads();

    // issue next tile's global loads; latency hides under this tile's compute
    if (t + 1 < t1) {
      const int kn = (t + 1) * 64;
      kpa = *(const bf16x8*)(Kh + (size_t)(kn + kr0) * HD + kc0);
      kpb = *(const bf16x8*)(Kh + (size_t)(kn + kr0 + 32) * HD + kc0);
      vpa = *(const bf16x8*)(Vth + (size_t)kr0 * NL + kn + kc0);
      vpb = *(const bf16x8*)(Vth + (size_t)(kr0 + 32) * NL + kn + kc0);
    }

    // SWAPPED QK^T: sacc[si][r] = S[s = kv0+si*16+lg*4+r][q = qg]
    f32x4 sacc[4];
#pragma unroll
    for (int si = 0; si < 4; ++si) sacc[si] = zero4;
#pragma unroll
    for (int kk = 0; kk < 2; ++kk) {
#pragma unroll
      for (int si = 0; si < 4; ++si) {
        bf16x8 kf = *(const bf16x8*)&Kt[si * 16 + lr][kk * 32 + lg * 8];
        sacc[si] = __builtin_amdgcn_mfma_f32_16x16x32_bf16(kf, qf[kk],
                                                           sacc[si], 0, 0, 0);
      }
    }

    // exp2 -> rcp sigmoid -> Horner -> causal mask; pack bf16 pairs in regs.
    // (K(q)=1+q-2q^2+3q^3 >= 1 on [0,1]: relu is provably dead.)
    unsigned pk[4][2];
#pragma unroll
    for (int si = 0; si < 4; ++si) {
      const int sb = kv0 + si * 16 + lg * 4;
      unsigned kbv[4];
#pragma unroll
      for (int r = 0; r < 4; ++r) {
        const float e = __builtin_amdgcn_exp2f(sacc[si][r] * ninv);
        const float qs = __builtin_amdgcn_rcpf(1.0f + e);
        float kvv = fmaf(qs, fmaf(qs, fmaf(qs, 3.0f, -2.0f), 1.0f), 1.0f);
        if (sb + r > qg) kvv = 0.0f;
        const __bf16 kb = (__bf16)kvv;
        den_l += (float)kb;  // den from rounded value -> num/den consistent
        kbv[r] = (unsigned)__builtin_bit_cast(unsigned short, kb);
      }
      pk[si][0] = kbv[0] | (kbv[1] << 16);
      pk[si][1] = kbv[2] | (kbv[3] << 16);
    }

    // PV: redistribute P via bpermute, then o_acc[n] += P(16x64) @ V tile n
#pragma unroll
    for (int kk = 0; kk < 2; ++kk) {
      const int sl = kk * 2, sh = kk * 2 + 1;
      const int a0 = __builtin_amdgcn_ds_bpermute(idxA, (int)pk[sl][0]);
      const int a1 = __builtin_amdgcn_ds_bpermute(idxA, (int)pk[sl][1]);
      const int b0 = __builtin_amdgcn_ds_bpermute(idxA + 64, (int)pk[sl][0]);
      const int b1 = __builtin_amdgcn_ds_bpermute(idxA + 64, (int)pk[sl][1]);
      const int c0 = __builtin_amdgcn_ds_bpermute(idxA, (int)pk[sh][0]);
      const int c1 = __builtin_amdgcn_ds_bpermute(idxA, (int)pk[sh][1]);
      const int d0 = __builtin_amdgcn_ds_bpermute(idxA + 64, (int)pk[sh][0]);
      const int d1 = __builtin_amdgcn_ds_bpermute(idxA + 64, (int)pk[sh][1]);
      i32x4 pw = {hi ? c0 : a0, hi ? c1 : a1, hi ? d0 : b0, hi ? d1 : b1};
      bf16x8 pf = __builtin_bit_cast(bf16x8, pw);
#pragma unroll
      for (int n = 0; n < 4; ++n) {
        bf16x8 vf = *(const bf16x8*)&Vt[n * 16 + lr][kk * 32 + lg * 8];
        o_acc[n] = __builtin_amdgcn_mfma_f32_16x16x32_bf16(pf, vf, o_acc[n],
                                                           0, 0, 0);
      }
    }
  }

  // den: combine the 4 lanes sharing lr (lane bits 4,5) -> full row sum
  den_l += __shfl_xor(den_l, 16, 64);
  den_l += __shfl_xor(den_l, 32, 64);

  if (SLOTTED) {
    // plain stores into this job's private slot
    float* nslot = numg + (((size_t)bh * NJOB + j) << 12);  // 64*64 floats
    const int lrow = w * 16 + lg * 4;  // + r
    if (lg == 0) {
      float* dslot = deng + (((size_t)bh * NJOB + j) << 6);
      dslot[w * 16 + lr] = den_l;
    }
#pragma unroll
    for (int n = 0; n < 4; ++n) {
      const int col = n * 16 + lr;
#pragma unroll
      for (int r = 0; r < 4; ++r) nslot[(lrow + r) * 64 + col] = o_acc[n][r];
    }
  } else {
    // fallback: device-scope f32 atomics into shared accumulators
    const int orow = q0 + w * 16 + lg * 4;  // + r
    if (lg == 0) atomicAdd(&deng[(size_t)bh * NL + q0 + w * 16 + lr], den_l);
#pragma unroll
    for (int n = 0; n < 4; ++n) {
      const int col = n * 16 + lr;
#pragma unroll
      for (int r = 0; r < 4; ++r)
        atomicAdd(&numg[((size_t)bh * NL + orow + r) * HD + col], o_acc[n][r]);
    }
  }
}

// ---------------------------------------------------------------------------
// Combine (slotted): AO[b][l][h*64+d] = (sum_c num_slot) / max(sum_c den, eps)
// Row l: qb = l>>6; chunks c = 0..qb/8, slot jj = cum[c] + qb - 8c with
// cum = {0,32,56,72}. Fixed order -> bitwise deterministic.
// ---------------------------------------------------------------------------
__global__ __launch_bounds__(256) void combine_slotted(
    const float* __restrict__ numS, const float* __restrict__ denS,
    __bf16* __restrict__ AO) {
  const int gid = blockIdx.x * 256 + threadIdx.x;  // 0 .. 524287
  const int d4 = gid & 15;
  const int row = gid >> 4;  // bh*NL + l
  const int bh = row >> 11, l = row & (NL - 1);
  const int b = bh >> 3, h = bh & 7;
  const int qb = l >> 6, lrow = l & 63;
  const int nc = (qb >> 3) + 1;
  const int cum[4] = {0, 32, 56, 72};

  f32x4 acc = {0.f, 0.f, 0.f, 0.f};
  float d = 0.f;
  for (int c = 0; c < nc; ++c) {
    const int jj = cum[c] + qb - 8 * c;
    const size_t sb = (size_t)bh * NJOB + jj;
    acc += *(const f32x4*)(numS + ((sb << 6) + lrow) * 64 + d4 * 4);
    d += denS[(sb << 6) + lrow];
  }
  const float idv = __builtin_amdgcn_rcpf(fmaxf(d, 1e-12f));
  bf16x4 o = {(__bf16)(acc[0] * idv), (__bf16)(acc[1] * idv),
              (__bf16)(acc[2] * idv), (__bf16)(acc[3] * idv)};
  *(bf16x4*)&AO[((size_t)b * NL + l) * NE + h * HD + d4 * 4] = o;
}

// Fallback combine (atomic layout): num (B,H,L,Hd), den (B,H,L)
__global__ __launch_bounds__(256) void combine_kernel(
    const float* __restrict__ numg, const float* __restrict__ deng,
    __bf16* __restrict__ AO) {
  const int gid = blockIdx.x * 256 + threadIdx.x;  // 0 .. 524287
  const int d4 = gid & 15;
  const int row = gid >> 4;  // bh*NL + l
  const int bh = row >> 11, l = row & (NL - 1);
  const int b = bh >> 3, h = bh & 7;
  f32x4 n4 = ((const f32x4*)numg)[gid];
  const float idv = __builtin_amdgcn_rcpf(fmaxf(deng[row], 1e-12f));
  bf16x4 o = {(__bf16)(n4[0] * idv), (__bf16)(n4[1] * idv),
              (__bf16)(n4[2] * idv), (__bf16)(n4[3] * idv)};
  *(bf16x4*)&AO[((size_t)b * NL + l) * NE + h * HD + d4 * 4] = o;
}

// ---------------------------------------------------------------------------
extern "C" void kernel_launch(void* const* d_in, const int* in_sizes, int n_in,
                              void* d_out, int out_size, void* d_ws,
                              size_t ws_size, hipStream_t stream) {
  const float* query = (const float*)d_in[0];
  const float* key_ = (const float*)d_in[1];
  const float* value = (const float*)d_in[2];
  const float* Wq = (const float*)d_in[3];
  const float* bq = (const float*)d_in[4];
  const float* Wk = (const float*)d_in[5];
  const float* bk = (const float*)d_in[6];
  const float* Wv = (const float*)d_in[7];
  const float* bv = (const float*)d_in[8];
  const float* Wo = (const float*)d_in[9];
  const float* bo = (const float*)d_in[10];
  const float* log_tau = (const float*)d_in[11];

  char* ws = (char*)d_ws;
  const size_t MB = 1024 * 1024;
  const bool slotted = (ws_size >= 55 * MB);

  // inputs (dead after qkv_gemm) always at 0/4/8 MB
  __bf16* xb = (__bf16*)(ws + 0 * MB);
  __bf16* kxb = (__bf16*)(ws + 4 * MB);
  __bf16* vxb = (__bf16*)(ws + 8 * MB);

  __bf16 *wqb, *wkb, *wvb, *wob, *Qh, *Kh, *VT, *AO;
  float *numb, *denb;
  if (slotted) {
    numb = (float*)(ws + 0 * MB);   // 16*80*64*64 f32 = 20 MB (overlays xb..)
    denb = (float*)(ws + 20 * MB);  // 16*80*64 f32 = 320 KB
    wqb = (__bf16*)(ws + 21 * MB);
    wkb = (__bf16*)(ws + 21 * MB + 512 * 1024);
    wvb = (__bf16*)(ws + 22 * MB);
    wob = (__bf16*)(ws + 22 * MB + 512 * 1024);
    Qh = (__bf16*)(ws + 23 * MB);
    Kh = (__bf16*)(ws + 27 * MB);
    VT = (__bf16*)(ws + 31 * MB);
    AO = (__bf16*)(ws + 35 * MB);
  } else {
    numb = (float*)(ws + 0 * MB);   // (B,H,L,Hd) f32 (8 MB)
    denb = (float*)(ws + 8 * MB);   // (B,H,L) f32 (128 KB)
    wqb = (__bf16*)(ws + 12 * MB);
    wkb = (__bf16*)(ws + 12 * MB + 512 * 1024);
    wvb = (__bf16*)(ws + 13 * MB);
    wob = (__bf16*)(ws + 13 * MB + 512 * 1024);
    Qh = (__bf16*)(ws + 14 * MB);
    Kh = (__bf16*)(ws + 18 * MB);
    VT = (__bf16*)(ws + 22 * MB);
    AO = (__bf16*)(ws + 26 * MB);
  }

  // single fused conversion launch: 3*2^19 + 4*2^16 float4 = 7168 blocks
  cvt_all<<<7168, 256, 0, stream>>>(query, key_, value, Wq, Wk, Wv, Wo, xb,
                                    kxb, vxb, wqb, wkb, wvb, wob);

  dim3 gq(NE / 128, NROW / 128, 3);  // (4, 32, 3) = 384 blocks
  qkv_gemm<<<gq, 256, 0, stream>>>(xb, kxb, vxb, wqb, wkb, wvb, bq, bk, bv, Qh,
                                   Kh, VT);

  dim3 ga(NJOB, NB * NH);  // 1280 jobs, each <=8 KV tiles
  if (slotted) {
    // no zero-init needed: every slot is fully written by its job
    attn_kernel<1><<<ga, 256, 0, stream>>>(Qh, Kh, VT, numb, denb, log_tau);
    combine_slotted<<<2048, 256, 0, stream>>>(numb, denb, AO);
  } else {
    hipMemsetAsync(ws, 0, 8 * MB + 128 * 1024, stream);
    attn_kernel<0><<<ga, 256, 0, stream>>>(Qh, Kh, VT, numb, denb, log_tau);
    combine_kernel<<<2048, 256, 0, stream>>>(numb, denb, AO);
  }

  dim3 gg(NE / 128, NROW / 128);  // (4, 32)
  out_gemm<<<gg, 256, 0, stream>>>(AO, wob, bo, (float*)d_out);
}

// Round 19
// 77.703 us; speedup vs baseline: 1.0178x; 1.0178x over previous
//
#include <hip/hip_runtime.h>
#include <hip/hip_bf16.h>

// ---------------------------------------------------------------------------
// MockModularAttention: Q/K/V proj -> sigmoid/Horner causal attention -> out proj
// B=2, L=2048, E=512, H=8, Hd=64. bf16 MFMA, fp32 accum.
// Attention: round-17 proven config (KV-split chunk=4, slotted atomic-free
// partials, single-buffer staging + T14 prefetch, swapped QK^T + bpermute).
// THIS ROUND: GEMMs use BK=64 (was 32) -> barrier pairs per GEMM halve
// (16 -> 8); MFMA K-order unchanged (bitwise-identical output).
// ---------------------------------------------------------------------------

typedef __attribute__((ext_vector_type(8))) __bf16 bf16x8;
typedef __attribute__((ext_vector_type(4))) __bf16 bf16x4;
typedef __attribute__((ext_vector_type(4))) float f32x4;
typedef __attribute__((ext_vector_type(4))) int i32x4;

#define NB 2
#define NL 2048
#define NE 512
#define NH 8
#define HD 64
#define NROW (NB * NL)  // 4096
#define NJOB 144        // KV-split jobs per (b,h), chunk=4

__device__ __forceinline__ void gload16(const void* g, void* l) {
  __builtin_amdgcn_global_load_lds(
      (const __attribute__((address_space(1))) void*)g,
      (__attribute__((address_space(3))) void*)l, 16, 0, 0);
}

// ---------------------------------------------------------------------------
// Single fused fp32->bf16 conversion: query,key_,value (each 2^19 float4)
// then Wq,Wk,Wv,Wo (each 2^16 float4). Grid: 7168 x 256 threads, exact.
// ---------------------------------------------------------------------------
__global__ __launch_bounds__(256) void cvt_all(
    const float* __restrict__ q, const float* __restrict__ k,
    const float* __restrict__ v, const float* __restrict__ w0,
    const float* __restrict__ w1, const float* __restrict__ w2,
    const float* __restrict__ w3, __bf16* __restrict__ qo,
    __bf16* __restrict__ ko, __bf16* __restrict__ vo, __bf16* __restrict__ o0,
    __bf16* __restrict__ o1, __bf16* __restrict__ o2,
    __bf16* __restrict__ o3) {
  const int gid = blockIdx.x * 256 + threadIdx.x;
  const float* s;
  __bf16* d;
  int i;
  if (gid < 3 * (1 << 19)) {
    const int seg = gid >> 19;
    i = gid & ((1 << 19) - 1);
    s = seg == 0 ? q : (seg == 1 ? k : v);
    d = seg == 0 ? qo : (seg == 1 ? ko : vo);
  } else {
    const int wid = gid - 3 * (1 << 19);
    const int seg = wid >> 16;
    i = wid & 0xFFFF;
    s = seg == 0 ? w0 : (seg == 1 ? w1 : (seg == 2 ? w2 : w3));
    d = seg == 0 ? o0 : (seg == 1 ? o1 : (seg == 2 ? o2 : o3));
  }
  float4 x = ((const float4*)s)[i];
  bf16x4 o = {(__bf16)x.x, (__bf16)x.y, (__bf16)x.z, (__bf16)x.w};
  ((bf16x4*)d)[i] = o;
}

// ---------------------------------------------------------------------------
// GEMM body: 128x128 tile, BK=64 (8 K-steps x 2 barriers), 4 waves,
// global_load_lds staging (linear dest: thread cidx -> As + cidx*8).
// MFMA K-order identical to the BK=32 version -> bitwise-identical acc.
// MODE 0: bf16 out, head layout (B,H,L,Hd).
// MODE 1: fp32 out, (row, col).
// MODE 2: bf16 out, TRANSPOSED head layout (B,H,Hd,L)  [for V]
// ---------------------------------------------------------------------------
template <int MODE>
__device__ __forceinline__ void gemm_body(const __bf16* __restrict__ A,
                                          const __bf16* __restrict__ W,
                                          const float* __restrict__ bias,
                                          __bf16* __restrict__ outb,
                                          float* __restrict__ outf) {
  __shared__ __align__(16) __bf16 As[128 * 64];
  __shared__ __align__(16) __bf16 Ws[128 * 64];

  const int tid = threadIdx.x;
  const int lane = tid & 63, w = tid >> 6;
  const int lr = lane & 15, lg = lane >> 4;
  const int brow = blockIdx.y * 128, bcol = blockIdx.x * 128;
  const int wr = (w >> 1) * 64, wc = (w & 1) * 64;

  f32x4 zero4 = {0.f, 0.f, 0.f, 0.f};
  f32x4 acc[4][4];
#pragma unroll
  for (int i = 0; i < 4; ++i)
#pragma unroll
    for (int j = 0; j < 4; ++j) acc[i][j] = zero4;

  for (int k0 = 0; k0 < NE; k0 += 64) {
    __syncthreads();
#pragma unroll
    for (int q = 0; q < 4; ++q) {
      const int cidx = tid + q * 256;          // 0..1023
      const int rr = cidx >> 3, cc = (cidx & 7) * 8;
      gload16(A + (size_t)(brow + rr) * NE + k0 + cc, As + cidx * 8);
      gload16(W + (size_t)(bcol + rr) * NE + k0 + cc, Ws + cidx * 8);
    }
    __syncthreads();

#pragma unroll
    for (int kk = 0; kk < 2; ++kk) {
      bf16x8 af[4], wf[4];
#pragma unroll
      for (int mi = 0; mi < 4; ++mi)
        af[mi] =
            *(const bf16x8*)(As + (wr + mi * 16 + lr) * 64 + kk * 32 + lg * 8);
#pragma unroll
      for (int ni = 0; ni < 4; ++ni)
        wf[ni] =
            *(const bf16x8*)(Ws + (wc + ni * 16 + lr) * 64 + kk * 32 + lg * 8);
#pragma unroll
      for (int mi = 0; mi < 4; ++mi)
#pragma unroll
        for (int ni = 0; ni < 4; ++ni)
          acc[mi][ni] = __builtin_amdgcn_mfma_f32_16x16x32_bf16(
              af[mi], wf[ni], acc[mi][ni], 0, 0, 0);
    }
  }

#pragma unroll
  for (int mi = 0; mi < 4; ++mi) {
#pragma unroll
    for (int ni = 0; ni < 4; ++ni) {
      const int col = bcol + wc + ni * 16 + lr;
      const float bv = bias[col];
#pragma unroll
      for (int r = 0; r < 4; ++r) {
        const int row = brow + wr + mi * 16 + lg * 4 + r;
        const float v = acc[mi][ni][r] + bv;
        if (MODE == 0) {
          const int b = row >> 11, l = row & (NL - 1);
          const int h = col >> 6, d = col & 63;
          outb[(((size_t)b * NH + h) * NL + l) * HD + d] = (__bf16)v;
        } else if (MODE == 2) {
          const int b = row >> 11, l = row & (NL - 1);
          const int h = col >> 6, d = col & 63;
          outb[(((size_t)b * NH + h) * HD + d) * NL + l] = (__bf16)v;
        } else {
          outf[(size_t)row * NE + col] = v;
        }
      }
    }
  }
}

// Fused Q/K/V projections: grid.z selects; V (z=2) writes transposed layout.
__global__ __launch_bounds__(256) void qkv_gemm(
    const __bf16* __restrict__ A0, const __bf16* __restrict__ A1,
    const __bf16* __restrict__ A2, const __bf16* __restrict__ W0,
    const __bf16* __restrict__ W1, const __bf16* __restrict__ W2,
    const float* __restrict__ b0, const float* __restrict__ b1,
    const float* __restrict__ b2, __bf16* __restrict__ O0,
    __bf16* __restrict__ O1, __bf16* __restrict__ O2) {
  const int z = blockIdx.z;
  if (z == 2) {
    gemm_body<2>(A2, W2, b2, O2, nullptr);
  } else {
    const __bf16* A = z == 0 ? A0 : A1;
    const __bf16* W = z == 0 ? W0 : W1;
    const float* bias = z == 0 ? b0 : b1;
    __bf16* O = z == 0 ? O0 : O1;
    gemm_body<0>(A, W, bias, O, nullptr);
  }
}

__global__ __launch_bounds__(256) void out_gemm(const __bf16* __restrict__ A,
                                                const __bf16* __restrict__ W,
                                                const float* __restrict__ bias,
                                                float* __restrict__ outf) {
  gemm_body<1>(A, W, bias, nullptr, outf);
}

// ---------------------------------------------------------------------------
// KV-split causal attention, sigmoid/Horner. Chunk=4, slotted partials.
// SWAPPED QK^T + bpermute P redistribution (round-15/17 proven, byte-exact).
// ---------------------------------------------------------------------------
template <int SLOTTED>
__global__ __launch_bounds__(256) void attn_kernel(
    const __bf16* __restrict__ Qg, const __bf16* __restrict__ Kg,
    const __bf16* __restrict__ VTg, float* __restrict__ numg,
    float* __restrict__ deng, const float* __restrict__ log_tau) {
  // rows padded to 72 bf16 (144 B = 9*16B): b128-aligned reads
  __shared__ __align__(16) __bf16 Kt[64][72];
  __shared__ __align__(16) __bf16 Vt[64][72];  // Vt[d][s] = V[s][d]

  // job -> (qb, c); c covers qb >= 4c. Counts per c: 32,28,24,20,16,12,8,4.
  const int j = blockIdx.x;
  int qb, c;
  if (j < 32) {
    c = 0; qb = j;
  } else if (j < 60) {
    c = 1; qb = j - 28;   // 4 + (j-32)
  } else if (j < 84) {
    c = 2; qb = j - 52;   // 8 + (j-60)
  } else if (j < 104) {
    c = 3; qb = j - 72;   // 12 + (j-84)
  } else if (j < 120) {
    c = 4; qb = j - 88;   // 16 + (j-104)
  } else if (j < 132) {
    c = 5; qb = j - 100;  // 20 + (j-120)
  } else if (j < 140) {
    c = 6; qb = j - 108;  // 24 + (j-132)
  } else {
    c = 7; qb = j - 112;  // 28 + (j-140)
  }
  const int bh = blockIdx.y;  // b*NH + h
  const __bf16* Qh = Qg + (size_t)bh * NL * HD;
  const __bf16* Kh = Kg + (size_t)bh * NL * HD;
  const __bf16* Vth = VTg + (size_t)bh * HD * NL;  // (Hd, L) for this head

  const int tid = threadIdx.x;
  const int lane = tid & 63, w = tid >> 6;
  const int lr = lane & 15, lg = lane >> 4;
  // sigmoid(s/(8*tau)) = rcp(1 + exp2(s*ninv)), ninv = -log2(e)/(8*tau)
  const float ninv = -1.44269504f / (8.0f * __expf(log_tau[0]));

  const int q0 = qb * 64;
  const int qg = q0 + w * 16 + lr;  // this lane's q-row (swapped layout)
  bf16x8 qf[2];
  qf[0] = *(const bf16x8*)(Qh + (size_t)qg * HD + lg * 8);
  qf[1] = *(const bf16x8*)(Qh + (size_t)qg * HD + 32 + lg * 8);

  f32x4 zero4 = {0.f, 0.f, 0.f, 0.f};
  f32x4 o_acc[4];
#pragma unroll
  for (int n = 0; n < 4; ++n) o_acc[n] = zero4;
  float den_l = 0.f;  // lane-local partial over this lane's s-subset

  const int t0 = c * 4;
  const int t1 = min(t0 + 4, qb + 1);

  // staging partition: thread -> rows {kr0, kr0+32}, cols kc0..kc0+7.
  const int kr0 = tid >> 3, kc0 = (tid & 7) * 8;

  // prologue: load tile t0 into registers
  bf16x8 kpa = *(const bf16x8*)(Kh + (size_t)(t0 * 64 + kr0) * HD + kc0);
  bf16x8 kpb = *(const bf16x8*)(Kh + (size_t)(t0 * 64 + kr0 + 32) * HD + kc0);
  bf16x8 vpa = *(const bf16x8*)(Vth + (size_t)kr0 * NL + t0 * 64 + kc0);
  bf16x8 vpb = *(const bf16x8*)(Vth + (size_t)(kr0 + 32) * NL + t0 * 64 + kc0);

  // bpermute byte-index of source lane A ((lg&1)*32 + lr); B = +16 lanes
  const int idxA = (((lane & 16) << 1) + lr) * 4;
  const bool hi = (lane & 32) != 0;  // lg>>1: selects si tile parity

  for (int t = t0; t < t1; ++t) {
    const int kv0 = t * 64;
    __syncthreads();  // previous iter's LDS reads done before overwrite
    *(bf16x8*)&Kt[kr0][kc0] = kpa;
    *(bf16x8*)&Kt[kr0 + 32][kc0] = kpb;
    *(bf16x8*)&Vt[kr0][kc0] = vpa;
    *(bf16x8*)&Vt[kr0 + 32][kc0] = vpb;
    __syncthreads();

    // issue next tile's global loads; latency hides under this tile's compute
    if (t + 1 < t1) {
      const int kn = (t + 1) * 64;
      kpa = *(const bf16x8*)(Kh + (size_t)(kn + kr0) * HD + kc0);
      kpb = *(const bf16x8*)(Kh + (size_t)(kn + kr0 + 32) * HD + kc0);
      vpa = *(const bf16x8*)(Vth + (size_t)kr0 * NL + kn + kc0);
      vpb = *(const bf16x8*)(Vth + (size_t)(kr0 + 32) * NL + kn + kc0);
    }

    // SWAPPED QK^T: sacc[si][r] = S[s = kv0+si*16+lg*4+r][q = qg]
    f32x4 sacc[4];
#pragma unroll
    for (int si = 0; si < 4; ++si) sacc[si] = zero4;
#pragma unroll
    for (int kk = 0; kk < 2; ++kk) {
#pragma unroll
      for (int si = 0; si < 4; ++si) {
        bf16x8 kf = *(const bf16x8*)&Kt[si * 16 + lr][kk * 32 + lg * 8];
        sacc[si] = __builtin_amdgcn_mfma_f32_16x16x32_bf16(kf, qf[kk],
                                                           sacc[si], 0, 0, 0);
      }
    }

    // exp2 -> rcp sigmoid -> Horner -> causal mask; pack bf16 pairs in regs.
    // (K(q)=1+q-2q^2+3q^3 >= 1 on [0,1]: relu is provably dead.)
    unsigned pk[4][2];
#pragma unroll
    for (int si = 0; si < 4; ++si) {
      const int sb = kv0 + si * 16 + lg * 4;
      unsigned kbv[4];
#pragma unroll
      for (int r = 0; r < 4; ++r) {
        const float e = __builtin_amdgcn_exp2f(sacc[si][r] * ninv);
        const float qs = __builtin_amdgcn_rcpf(1.0f + e);
        float kvv = fmaf(qs, fmaf(qs, fmaf(qs, 3.0f, -2.0f), 1.0f), 1.0f);
        if (sb + r > qg) kvv = 0.0f;
        const __bf16 kb = (__bf16)kvv;
        den_l += (float)kb;  // den from rounded value -> num/den consistent
        kbv[r] = (unsigned)__builtin_bit_cast(unsigned short, kb);
      }
      pk[si][0] = kbv[0] | (kbv[1] << 16);
      pk[si][1] = kbv[2] | (kbv[3] << 16);
    }

    // PV: redistribute P via bpermute, then o_acc[n] += P(16x64) @ V tile n
#pragma unroll
    for (int kk = 0; kk < 2; ++kk) {
      const int sl = kk * 2, sh = kk * 2 + 1;
      const int a0 = __builtin_amdgcn_ds_bpermute(idxA, (int)pk[sl][0]);
      const int a1 = __builtin_amdgcn_ds_bpermute(idxA, (int)pk[sl][1]);
      const int b0 = __builtin_amdgcn_ds_bpermute(idxA + 64, (int)pk[sl][0]);
      const int b1 = __builtin_amdgcn_ds_bpermute(idxA + 64, (int)pk[sl][1]);
      const int c0 = __builtin_amdgcn_ds_bpermute(idxA, (int)pk[sh][0]);
      const int c1 = __builtin_amdgcn_ds_bpermute(idxA, (int)pk[sh][1]);
      const int d0 = __builtin_amdgcn_ds_bpermute(idxA + 64, (int)pk[sh][0]);
      const int d1 = __builtin_amdgcn_ds_bpermute(idxA + 64, (int)pk[sh][1]);
      i32x4 pw = {hi ? c0 : a0, hi ? c1 : a1, hi ? d0 : b0, hi ? d1 : b1};
      bf16x8 pf = __builtin_bit_cast(bf16x8, pw);
#pragma unroll
      for (int n = 0; n < 4; ++n) {
        bf16x8 vf = *(const bf16x8*)&Vt[n * 16 + lr][kk * 32 + lg * 8];
        o_acc[n] = __builtin_amdgcn_mfma_f32_16x16x32_bf16(pf, vf, o_acc[n],
                                                           0, 0, 0);
      }
    }
  }

  // den: combine the 4 lanes sharing lr (lane bits 4,5) -> full row sum
  den_l += __shfl_xor(den_l, 16, 64);
  den_l += __shfl_xor(den_l, 32, 64);

  if (SLOTTED) {
    // plain stores into this job's private slot
    float* nslot = numg + (((size_t)bh * NJOB + j) << 12);  // 64*64 floats
    const int lrow = w * 16 + lg * 4;  // + r
    if (lg == 0) {
      float* dslot = deng + (((size_t)bh * NJOB + j) << 6);
      dslot[w * 16 + lr] = den_l;
    }
#pragma unroll
    for (int n = 0; n < 4; ++n) {
      const int col = n * 16 + lr;
#pragma unroll
      for (int r = 0; r < 4; ++r) nslot[(lrow + r) * 64 + col] = o_acc[n][r];
    }
  } else {
    // fallback: device-scope f32 atomics into shared accumulators
    const int orow = q0 + w * 16 + lg * 4;  // + r
    if (lg == 0) atomicAdd(&deng[(size_t)bh * NL + q0 + w * 16 + lr], den_l);
#pragma unroll
    for (int n = 0; n < 4; ++n) {
      const int col = n * 16 + lr;
#pragma unroll
      for (int r = 0; r < 4; ++r)
        atomicAdd(&numg[((size_t)bh * NL + orow + r) * HD + col], o_acc[n][r]);
    }
  }
}

// ---------------------------------------------------------------------------
// Combine (slotted): AO[b][l][h*64+d] = (sum_c num_slot) / max(sum_c den, eps)
// Row l belongs to q-tile qb=l>>6; its chunks are c=0..qb/4 with job index
// j = qb + 2c(15-c). Fixed summation order -> bitwise deterministic.
// ---------------------------------------------------------------------------
__global__ __launch_bounds__(256) void combine_slotted(
    const float* __restrict__ numS, const float* __restrict__ denS,
    __bf16* __restrict__ AO) {
  const int gid = blockIdx.x * 256 + threadIdx.x;  // 0 .. 524287
  const int d4 = gid & 15;
  const int row = gid >> 4;  // bh*NL + l
  const int bh = row >> 11, l = row & (NL - 1);
  const int b = bh >> 3, h = bh & 7;
  const int qb = l >> 6, lrow = l & 63;
  const int nc = (qb >> 2) + 1;

  f32x4 acc = {0.f, 0.f, 0.f, 0.f};
  float d = 0.f;
  for (int c = 0; c < nc; ++c) {
    const int jj = qb + 2 * c * (15 - c);
    const size_t sb = (size_t)bh * NJOB + jj;
    acc += *(const f32x4*)(numS + ((sb << 6) + lrow) * 64 + d4 * 4);
    d += denS[(sb << 6) + lrow];
  }
  const float idv = __builtin_amdgcn_rcpf(fmaxf(d, 1e-12f));
  bf16x4 o = {(__bf16)(acc[0] * idv), (__bf16)(acc[1] * idv),
              (__bf16)(acc[2] * idv), (__bf16)(acc[3] * idv)};
  *(bf16x4*)&AO[((size_t)b * NL + l) * NE + h * HD + d4 * 4] = o;
}

// Fallback combine (atomic layout): num (B,H,L,Hd), den (B,H,L)
__global__ __launch_bounds__(256) void combine_kernel(
    const float* __restrict__ numg, const float* __restrict__ deng,
    __bf16* __restrict__ AO) {
  const int gid = blockIdx.x * 256 + threadIdx.x;  // 0 .. 524287
  const int d4 = gid & 15;
  const int row = gid >> 4;  // bh*NL + l
  const int bh = row >> 11, l = row & (NL - 1);
  const int b = bh >> 3, h = bh & 7;
  f32x4 n4 = ((const f32x4*)numg)[gid];
  const float idv = __builtin_amdgcn_rcpf(fmaxf(deng[row], 1e-12f));
  bf16x4 o = {(__bf16)(n4[0] * idv), (__bf16)(n4[1] * idv),
              (__bf16)(n4[2] * idv), (__bf16)(n4[3] * idv)};
  *(bf16x4*)&AO[((size_t)b * NL + l) * NE + h * HD + d4 * 4] = o;
}

// ---------------------------------------------------------------------------
extern "C" void kernel_launch(void* const* d_in, const int* in_sizes, int n_in,
                              void* d_out, int out_size, void* d_ws,
                              size_t ws_size, hipStream_t stream) {
  const float* query = (const float*)d_in[0];
  const float* key_ = (const float*)d_in[1];
  const float* value = (const float*)d_in[2];
  const float* Wq = (const float*)d_in[3];
  const float* bq = (const float*)d_in[4];
  const float* Wk = (const float*)d_in[5];
  const float* bk = (const float*)d_in[6];
  const float* Wv = (const float*)d_in[7];
  const float* bv = (const float*)d_in[8];
  const float* Wo = (const float*)d_in[9];
  const float* bo = (const float*)d_in[10];
  const float* log_tau = (const float*)d_in[11];

  char* ws = (char*)d_ws;
  const size_t MB = 1024 * 1024;
  const bool slotted = (ws_size >= 55 * MB);

  // inputs (dead after qkv_gemm) always at 0/4/8 MB
  __bf16* xb = (__bf16*)(ws + 0 * MB);
  __bf16* kxb = (__bf16*)(ws + 4 * MB);
  __bf16* vxb = (__bf16*)(ws + 8 * MB);

  __bf16 *wqb, *wkb, *wvb, *wob, *Qh, *Kh, *VT, *AO;
  float *numb, *denb;
  if (slotted) {
    numb = (float*)(ws + 0 * MB);   // 16*144*64*64 f32 = 36 MB (overlays xb..)
    denb = (float*)(ws + 36 * MB);  // 16*144*64 f32 = 576 KB
    wqb = (__bf16*)(ws + 37 * MB);
    wkb = (__bf16*)(ws + 37 * MB + 512 * 1024);
    wvb = (__bf16*)(ws + 38 * MB);
    wob = (__bf16*)(ws + 38 * MB + 512 * 1024);
    Qh = (__bf16*)(ws + 39 * MB);
    Kh = (__bf16*)(ws + 43 * MB);
    VT = (__bf16*)(ws + 47 * MB);
    AO = (__bf16*)(ws + 51 * MB);
  } else {
    numb = (float*)(ws + 0 * MB);   // (B,H,L,Hd) f32 (8 MB)
    denb = (float*)(ws + 8 * MB);   // (B,H,L) f32 (128 KB)
    wqb = (__bf16*)(ws + 12 * MB);
    wkb = (__bf16*)(ws + 12 * MB + 512 * 1024);
    wvb = (__bf16*)(ws + 13 * MB);
    wob = (__bf16*)(ws + 13 * MB + 512 * 1024);
    Qh = (__bf16*)(ws + 14 * MB);
    Kh = (__bf16*)(ws + 18 * MB);
    VT = (__bf16*)(ws + 22 * MB);
    AO = (__bf16*)(ws + 26 * MB);
  }

  // single fused conversion launch: 3*2^19 + 4*2^16 float4 = 7168 blocks
  cvt_all<<<7168, 256, 0, stream>>>(query, key_, value, Wq, Wk, Wv, Wo, xb,
                                    kxb, vxb, wqb, wkb, wvb, wob);

  dim3 gq(NE / 128, NROW / 128, 3);  // (4, 32, 3) = 384 blocks
  qkv_gemm<<<gq, 256, 0, stream>>>(xb, kxb, vxb, wqb, wkb, wvb, bq, bk, bv, Qh,
                                   Kh, VT);

  dim3 ga(NJOB, NB * NH);  // 2304 jobs, each <=4 KV tiles
  if (slotted) {
    // no zero-init needed: every slot is fully written by its job
    attn_kernel<1><<<ga, 256, 0, stream>>>(Qh, Kh, VT, numb, denb, log_tau);
    combine_slotted<<<2048, 256, 0, stream>>>(numb, denb, AO);
  } else {
    hipMemsetAsync(ws, 0, 8 * MB + 128 * 1024, stream);
    attn_kernel<0><<<ga, 256, 0, stream>>>(Qh, Kh, VT, numb, denb, log_tau);
    combine_kernel<<<2048, 256, 0, stream>>>(numb, denb, AO);
  }

  dim3 gg(NE / 128, NROW / 128);  // (4, 32)
  out_gemm<<<gg, 256, 0, stream>>>(AO, wob, bo, (float*)d_out);
}